// Round 13
// baseline (531.038 us; speedup 1.0000x reference)
//
#include <hip/hip_runtime.h>
#include <hip/hip_fp16.h>
#include <math.h>

// ---------------------------------------------------------------------------
// DeepECCNet: 3-layer gated graph conv + t-gate + MLP head.
// v22: 499.6 us (best). v23/v24: NT-csr-loads +60, {gemm512 + NT-store} +22
//      (measured directly in v24; R11's "-5" residual attribution was wrong).
//      All three reverted -> v22 core.
// v25: rank atomic-wall probe: counts8[part][t], part = blockIdx&7 (matches
//      round-robin block->XCD). If atomics execute XCD-locally on private
//      lines -> 8x RMW parallelism (rank 67 -> ~25us). If fabric-central ->
//      null (+4us scan1/scatter). slot packs (lrank<<3)|part; scan1 folds 8
//      partials into per-(part,t) offsets in place; scatter adds offset.
//      counts8 = own 3.2MB alloc (scatter reads it; no csr alias).
// ---------------------------------------------------------------------------

typedef _Float16 f16x8 __attribute__((ext_vector_type(8)));
typedef float f32x4 __attribute__((ext_vector_type(4)));

__device__ __forceinline__ float sigmoidf_(float v) { return 1.f / (1.f + expf(-v)); }

__global__ void sentinel_kernel(float* __restrict__ out, int n, float val) {
  int i = blockIdx.x * 256 + threadIdx.x;
  if (i < n) out[i] = val;
}

// ---- init: zero 8-way partitioned counts + detect int64 edge_index ---------
__global__ void init_kernel(const int* __restrict__ ei, int* __restrict__ flag,
                            int* __restrict__ counts8, int n) {
  int i = blockIdx.x * 256 + threadIdx.x;
  if (i < n * 8) counts8[i] = 0;
  if (i == 0) {
    int all0 = 1;
    for (int k = 1; k < 512; k += 2) {
      if (ei[k] != 0) { all0 = 0; break; }
    }
    *flag = all0;
  }
}

// ---- rank: slot[e] = (local_rank<<3)|part via partitioned counting atomic --
__global__ void rank_kernel(const int* __restrict__ ei, int E, int n,
                            const int* __restrict__ flag,
                            int* __restrict__ slot, int* __restrict__ counts8) {
  int e = blockIdx.x * blockDim.x + threadIdx.x;
  if (e >= E) return;
  int part = blockIdx.x & 7;
  int t;
  if (*flag) {
    t = (int)((const long long*)ei)[(size_t)E + e];
  } else {
    t = ei[(size_t)E + e];
  }
  if ((unsigned)t < (unsigned)n) {
    int lr = atomicAdd(&counts8[(size_t)part * n + t], 1);
    slot[e] = (lr << 3) | part;
  } else {
    slot[e] = -1;
  }
}

// ---- h0 = fp16(x[:, 1:]); x0 = x[:, 0] -------------------------------------
__global__ void slice_kernel(const float* __restrict__ x, _Float16* __restrict__ h,
                             float* __restrict__ x0, int n) {
  int idx = blockIdx.x * blockDim.x + threadIdx.x;
  if (idx < n * 128) {
    int node = idx >> 7;
    int k = idx & 127;
    h[idx] = (_Float16)x[(size_t)node * 129 + 1 + k];
  }
  if (idx < n) x0[idx] = x[(size_t)idx * 129];
}

// ---- scan1: fold 8 partials -> per-(part,t) offsets (in place) + node scan -
__global__ void scan1_kernel(int* __restrict__ counts8, int n,
                             int* __restrict__ starts, int* __restrict__ bsums) {
  __shared__ int tmp[256];
  int i = blockIdx.x * 256 + threadIdx.x;
  int v = 0;
  if (i < n) {
    int off = 0;
#pragma unroll
    for (int x = 0; x < 8; x++) {
      size_t idx = (size_t)x * n + i;
      int cx = counts8[idx];
      counts8[idx] = off;   // exclusive offset of partition x within node i
      off += cx;
    }
    v = off;                // total degree of node i
  }
  tmp[threadIdx.x] = v;
  __syncthreads();
  for (int off = 1; off < 256; off <<= 1) {
    int t = (threadIdx.x >= (unsigned)off) ? tmp[threadIdx.x - off] : 0;
    __syncthreads();
    tmp[threadIdx.x] += t;
    __syncthreads();
  }
  if (i <= n) starts[i] = tmp[threadIdx.x] - v;  // block-local exclusive
  if (threadIdx.x == 255) bsums[blockIdx.x] = tmp[255];
}

__global__ void scan2_kernel(int* __restrict__ bsums, int nb) {
  __shared__ int tmp[512];
  int v = (threadIdx.x < (unsigned)nb) ? bsums[threadIdx.x] : 0;
  tmp[threadIdx.x] = v;
  __syncthreads();
  for (int off = 1; off < 512; off <<= 1) {
    int t = (threadIdx.x >= (unsigned)off) ? tmp[threadIdx.x - off] : 0;
    __syncthreads();
    tmp[threadIdx.x] += t;
    __syncthreads();
  }
  if (threadIdx.x < (unsigned)nb) bsums[threadIdx.x] = tmp[threadIdx.x] - v;  // exclusive
}

// ---- fused B: scatter (csr build) + tnet head ------------------------------
__global__ __launch_bounds__(256) void scatter_head_kernel(
    const int* __restrict__ ei, const int* __restrict__ slot,
    const int* __restrict__ starts, const int* __restrict__ bsums,
    const int* __restrict__ counts8,
    const float* __restrict__ ea, int E, int n, const int* __restrict__ flag,
    const float* __restrict__ w0p, const float* __restrict__ w1p,
    const float* __restrict__ w2p, uint2* __restrict__ csr, int sgrid,
    const _Float16* __restrict__ h, const float* __restrict__ extra,
    const float* __restrict__ W1, const float* __restrict__ b1,
    const float* __restrict__ w2, const float* __restrict__ b2,
    float* __restrict__ out, int hrow0, int xrow) {
  if (blockIdx.x < (unsigned)sgrid) {
    // ---------------- scatter role ----------------
    float w0 = w0p[0], w1 = w1p[0], w2v_ = w2p[0];
    int f64 = *flag;
    const long long* e64 = (const long long*)ei;
    int base = blockIdx.x * 256 + threadIdx.x;
    int stride = sgrid * 256;
#pragma unroll
    for (int u = 0; u < 4; u++) {
      int e = base + u * stride;
      if (e < E) {
        int sl = slot[e];
        if (sl >= 0) {
          int s, t;
          if (f64) {
            s = (int)e64[e];
            t = (int)e64[(size_t)E + e];
          } else {
            s = ei[e];
            t = ei[(size_t)E + e];
          }
          int part = sl & 7, lrank = sl >> 3;
          int pos = starts[t] + bsums[t >> 8] +
                    counts8[(size_t)part * n + t] + lrank;
          if ((unsigned)pos < (unsigned)E) {
            float a = ea[e];
            unsigned sn = (unsigned)min(max(s, 0), min(n - 1, 0x1ffff));
            unsigned g0 = (unsigned)__float2uint_rn(sigmoidf_(a * w0) * 32767.f);
            unsigned g1 = (unsigned)__float2uint_rn(sigmoidf_(a * w1) * 32767.f);
            unsigned g2 = (unsigned)__float2uint_rn(sigmoidf_(a * w2v_) * 32767.f);
            csr[pos] = make_uint2(sn | (g0 << 17), g1 | (g2 << 15));
          }
        }
      }
    }
  } else {
    // ---------------- head role (tnet) ----------------
    __shared__ __align__(16) _Float16 sB[4 * 4 * 64 * 8];  // 16 KB
    __shared__ float sWx[64], sB1[64], sW2[64];
    for (int idx = threadIdx.x; idx < 8192; idx += 256) {
      int k = idx >> 6, col = idx & 63;
      float w = W1[(size_t)(hrow0 + k) * 64 + col];
      int ks = k >> 5, quad = (k >> 3) & 3, j = k & 7;
      int nt = col >> 4, cl = col & 15;
      sB[(((ks * 4 + nt) * 64) + quad * 16 + cl) * 8 + j] = (_Float16)w;
    }
    if (threadIdx.x < 64) {
      sWx[threadIdx.x] = W1[(size_t)xrow * 64 + threadIdx.x];
      sB1[threadIdx.x] = b1[threadIdx.x];
      sW2[threadIdx.x] = w2[threadIdx.x];
    }
    __syncthreads();
    int hbid = blockIdx.x - sgrid;
    int wv = threadIdx.x >> 6, lane = threadIdx.x & 63;
    int quad = lane >> 4, l15 = lane & 15;
    int n0 = (hbid * 4 + wv) * 16;
    if (n0 >= n) return;
    int node_a = min(n0 + l15, n - 1);
    const _Float16* hrow = h + (size_t)node_a * 128 + quad * 8;

    f32x4 acc[4];
#pragma unroll
    for (int t = 0; t < 4; t++) acc[t] = (f32x4){0.f, 0.f, 0.f, 0.f};
    for (int ks = 0; ks < 4; ks++) {
      f16x8 afrag = *(const f16x8*)(hrow + ks * 32);
      const f16x8* bp = (const f16x8*)sB;
#pragma unroll
      for (int t = 0; t < 4; t++) {
        f16x8 bfrag = bp[(ks * 4 + t) * 64 + lane];
        acc[t] = __builtin_amdgcn_mfma_f32_16x16x32_f16(afrag, bfrag, acc[t], 0, 0, 0);
      }
    }
    float b2v = b2[0];
    float xv[4], part[4] = {0.f, 0.f, 0.f, 0.f};
#pragma unroll
    for (int r = 0; r < 4; r++) xv[r] = extra[min(n0 + quad * 4 + r, n - 1)];
#pragma unroll
    for (int t = 0; t < 4; t++) {
      int col = t * 16 + l15;
      float wx = sWx[col], bb = sB1[col], w2v = sW2[col];
#pragma unroll
      for (int r = 0; r < 4; r++) {
        float u = fmaxf(acc[t][r] + xv[r] * wx + bb, 0.f);
        part[r] += u * w2v;
      }
    }
#pragma unroll
    for (int r = 0; r < 4; r++) {
      float p = part[r];
      p += __shfl_xor(p, 1); p += __shfl_xor(p, 2);
      p += __shfl_xor(p, 4); p += __shfl_xor(p, 8);
      int node = n0 + quad * 4 + r;
      if (l15 == 0 && node < n) out[node] = sigmoidf_(p + b2v);
    }
  }
}

// ---- standalone MFMA head (final mlp) --------------------------------------
__global__ __launch_bounds__(256) void head_mfma_kernel(const _Float16* __restrict__ h,
    const float* __restrict__ extra, const float* __restrict__ W1,
    const float* __restrict__ b1, const float* __restrict__ w2,
    const float* __restrict__ b2, float* __restrict__ out, int n,
    int hrow0, int xrow) {
  __shared__ __align__(16) _Float16 sB[4 * 4 * 64 * 8];  // 16 KB, B-frag order
  __shared__ float sWx[64], sB1[64], sW2[64];
  for (int idx = threadIdx.x; idx < 8192; idx += 256) {
    int k = idx >> 6, col = idx & 63;
    float w = W1[(size_t)(hrow0 + k) * 64 + col];
    int ks = k >> 5, quad = (k >> 3) & 3, j = k & 7;
    int nt = col >> 4, cl = col & 15;
    sB[(((ks * 4 + nt) * 64) + quad * 16 + cl) * 8 + j] = (_Float16)w;
  }
  if (threadIdx.x < 64) {
    sWx[threadIdx.x] = W1[(size_t)xrow * 64 + threadIdx.x];
    sB1[threadIdx.x] = b1[threadIdx.x];
    sW2[threadIdx.x] = w2[threadIdx.x];
  }
  __syncthreads();
  int wv = threadIdx.x >> 6, lane = threadIdx.x & 63;
  int quad = lane >> 4, l15 = lane & 15;
  int n0 = (blockIdx.x * 4 + wv) * 16;
  if (n0 >= n) return;
  int node_a = min(n0 + l15, n - 1);
  const _Float16* hrow = h + (size_t)node_a * 128 + quad * 8;

  f32x4 acc[4];
#pragma unroll
  for (int t = 0; t < 4; t++) acc[t] = (f32x4){0.f, 0.f, 0.f, 0.f};
  for (int ks = 0; ks < 4; ks++) {
    f16x8 afrag = *(const f16x8*)(hrow + ks * 32);
    const f16x8* bp = (const f16x8*)sB;
#pragma unroll
    for (int t = 0; t < 4; t++) {
      f16x8 bfrag = bp[(ks * 4 + t) * 64 + lane];
      acc[t] = __builtin_amdgcn_mfma_f32_16x16x32_f16(afrag, bfrag, acc[t], 0, 0, 0);
    }
  }
  float b2v = b2[0];
  float xv[4], part[4] = {0.f, 0.f, 0.f, 0.f};
#pragma unroll
  for (int r = 0; r < 4; r++) xv[r] = extra[min(n0 + quad * 4 + r, n - 1)];
#pragma unroll
  for (int t = 0; t < 4; t++) {
    int col = t * 16 + l15;
    float wx = sWx[col], bb = sB1[col], w2v = sW2[col];
#pragma unroll
    for (int r = 0; r < 4; r++) {
      float u = fmaxf(acc[t][r] + xv[r] * wx + bb, 0.f);
      part[r] += u * w2v;
    }
  }
#pragma unroll
  for (int r = 0; r < 4; r++) {
    float p = part[r];
    p += __shfl_xor(p, 1); p += __shfl_xor(p, 2);
    p += __shfl_xor(p, 4); p += __shfl_xor(p, 8);
    int node = n0 + quad * 4 + r;
    if (l15 == 0 && node < n) out[node] = sigmoidf_(p + b2v);
  }
}

// ---- MFMA GEMM: ht8/scales = rowquant(h16 @ W + b) -------------------------
__global__ __launch_bounds__(256) void gemm_mfma_kernel(const _Float16* __restrict__ h,
    const float* __restrict__ Wg, const float* __restrict__ b,
    unsigned char* __restrict__ out8, float* __restrict__ scales, int n) {
  __shared__ __align__(16) _Float16 sB[4 * 8 * 64 * 8];  // 32 KB
  for (int i = threadIdx.x; i < 4096; i += 256) {  // i = float4 index over W
    int k = i >> 5;
    int n4 = (i & 31) * 4;
    float4 w4 = ((const float4*)Wg)[i];
    int ks = k >> 5, quad = (k >> 3) & 3, j = k & 7;
#pragma unroll
    for (int c = 0; c < 4; c++) {
      int col = n4 + c;
      int nt = col >> 4, cl = col & 15;
      sB[(((ks * 8 + nt) * 64) + quad * 16 + cl) * 8 + j] =
          (_Float16)((const float*)&w4)[c];
    }
  }
  __syncthreads();
  int wv = threadIdx.x >> 6, lane = threadIdx.x & 63;
  int quad = lane >> 4, l15 = lane & 15;
  int tiles = (n + 63) >> 6;
  for (int tile = blockIdx.x; tile < tiles; tile += gridDim.x) {
    int n0 = (tile * 4 + wv) * 16;
    if (n0 >= n) continue;
    int node_a = min(n0 + l15, n - 1);
    const _Float16* hrow = h + (size_t)node_a * 128 + quad * 8;

    f32x4 acc[8];
#pragma unroll
    for (int t = 0; t < 8; t++) acc[t] = (f32x4){0.f, 0.f, 0.f, 0.f};

    for (int ks = 0; ks < 4; ks++) {
      f16x8 afrag = *(const f16x8*)(hrow + ks * 32);
      const f16x8* bp = (const f16x8*)(sB + ks * 8 * 64 * 8);
#pragma unroll
      for (int t = 0; t < 8; t++) {
        f16x8 bfrag = bp[t * 64 + lane];
        acc[t] = __builtin_amdgcn_mfma_f32_16x16x32_f16(afrag, bfrag, acc[t], 0, 0, 0);
      }
    }
    // add bias in place, then per-row absmax (row = 16 l15-lanes x 8 t-cols)
#pragma unroll
    for (int t = 0; t < 8; t++) {
      float bias = b[t * 16 + l15];
#pragma unroll
      for (int r = 0; r < 4; r++) acc[t][r] += bias;
    }
    float mx[4] = {0.f, 0.f, 0.f, 0.f};
#pragma unroll
    for (int t = 0; t < 8; t++)
#pragma unroll
      for (int r = 0; r < 4; r++) mx[r] = fmaxf(mx[r], fabsf(acc[t][r]));
#pragma unroll
    for (int m = 1; m <= 8; m <<= 1) {
#pragma unroll
      for (int r = 0; r < 4; r++) mx[r] = fmaxf(mx[r], __shfl_xor(mx[r], m));
    }
#pragma unroll
    for (int r = 0; r < 4; r++) {
      int node = n0 + quad * 4 + r;
      if (node >= n) continue;
      float inv = (mx[r] > 0.f) ? 127.f / mx[r] : 0.f;
      if (l15 == 0) scales[node] = mx[r] * (1.f / 127.f);
#pragma unroll
      for (int t = 0; t < 8; t++) {
        int u = (int)rintf(acc[t][r] * inv) + 128;
        u = min(max(u, 0), 255);
        out8[(size_t)node * 128 + t * 16 + l15] = (unsigned char)u;
      }
    }
  }
}

// ---- aggregation: int8 rows, edge-pair halves, plain cached csr loads ------
template <int LAYER>
__device__ __forceinline__ float gate_(uint2 r) {
  const float inv = 1.f / 32767.f;
  if (LAYER == 0) return (float)(r.x >> 17) * inv;
  if (LAYER == 1) return (float)(r.y & 0x7fffu) * inv;
  return (float)(r.y >> 15) * inv;
}

#define ACC4(u, g)                                   \
  a0 += (float)((u) & 0xffu) * (g);                  \
  a1 += (float)(((u) >> 8) & 0xffu) * (g);           \
  a2 += (float)(((u) >> 16) & 0xffu) * (g);          \
  a3 += (float)((u) >> 24) * (g);

template <int LAYER>
__global__ __launch_bounds__(256) void agg_kernel(const unsigned char* __restrict__ ht8,
    const float* __restrict__ scales, const uint2* __restrict__ csr,
    const int* __restrict__ starts, const int* __restrict__ bsums,
    const float* __restrict__ wp, __half2* __restrict__ hout, int n) {
  int wv = threadIdx.x >> 6, lane = threadIdx.x & 63;
  int node = blockIdx.x * 4 + wv;
  if (node >= n) return;
  int s = starts[node] + bsums[node >> 8];
  int c = starts[node + 1] + bsums[(node + 1) >> 8] - s;
  float gs = sigmoidf_(wp[0]);
  int sub = lane & 31, p = lane >> 5;
  unsigned sub4 = (unsigned)sub * 4u;

  // self term: half 0 only (half 1 gets g=0)
  unsigned su = *(const unsigned*)(ht8 + (unsigned)node * 128u + sub4);
  float gsc = (p == 0) ? gs * scales[node] : 0.f;
  float sgs = gsc;
  float a0 = 0.f, a1 = 0.f, a2 = 0.f, a3 = 0.f;
  ACC4(su, gsc)

  int j = 0;
  for (; j + 16 <= c; j += 16) {  // 8 pairs in flight: half p does j+2q+p
    uint2 r0 = csr[s + j + 0 + p],  r1 = csr[s + j + 2 + p];
    uint2 r2 = csr[s + j + 4 + p],  r3 = csr[s + j + 6 + p];
    uint2 r4 = csr[s + j + 8 + p],  r5 = csr[s + j + 10 + p];
    uint2 r6 = csr[s + j + 12 + p], r7 = csr[s + j + 14 + p];
    unsigned i0 = r0.x & 0x1ffffu, i1 = r1.x & 0x1ffffu;
    unsigned i2 = r2.x & 0x1ffffu, i3 = r3.x & 0x1ffffu;
    unsigned i4 = r4.x & 0x1ffffu, i5 = r5.x & 0x1ffffu;
    unsigned i6 = r6.x & 0x1ffffu, i7 = r7.x & 0x1ffffu;
    unsigned u0 = *(const unsigned*)(ht8 + i0 * 128u + sub4);
    unsigned u1 = *(const unsigned*)(ht8 + i1 * 128u + sub4);
    unsigned u2 = *(const unsigned*)(ht8 + i2 * 128u + sub4);
    unsigned u3 = *(const unsigned*)(ht8 + i3 * 128u + sub4);
    unsigned u4 = *(const unsigned*)(ht8 + i4 * 128u + sub4);
    unsigned u5 = *(const unsigned*)(ht8 + i5 * 128u + sub4);
    unsigned u6 = *(const unsigned*)(ht8 + i6 * 128u + sub4);
    unsigned u7 = *(const unsigned*)(ht8 + i7 * 128u + sub4);
    float g0 = gate_<LAYER>(r0) * scales[i0];
    float g1 = gate_<LAYER>(r1) * scales[i1];
    float g2 = gate_<LAYER>(r2) * scales[i2];
    float g3 = gate_<LAYER>(r3) * scales[i3];
    float g4 = gate_<LAYER>(r4) * scales[i4];
    float g5 = gate_<LAYER>(r5) * scales[i5];
    float g6 = gate_<LAYER>(r6) * scales[i6];
    float g7 = gate_<LAYER>(r7) * scales[i7];
    sgs += g0 + g1 + g2 + g3 + g4 + g5 + g6 + g7;
    ACC4(u0, g0) ACC4(u1, g1) ACC4(u2, g2) ACC4(u3, g3)
    ACC4(u4, g4) ACC4(u5, g5) ACC4(u6, g6) ACC4(u7, g7)
  }
  for (; j + 8 <= c; j += 8) {   // 4 pairs
    uint2 r0 = csr[s + j + 0 + p], r1 = csr[s + j + 2 + p];
    uint2 r2 = csr[s + j + 4 + p], r3 = csr[s + j + 6 + p];
    unsigned i0 = r0.x & 0x1ffffu, i1 = r1.x & 0x1ffffu;
    unsigned i2 = r2.x & 0x1ffffu, i3 = r3.x & 0x1ffffu;
    unsigned u0 = *(const unsigned*)(ht8 + i0 * 128u + sub4);
    unsigned u1 = *(const unsigned*)(ht8 + i1 * 128u + sub4);
    unsigned u2 = *(const unsigned*)(ht8 + i2 * 128u + sub4);
    unsigned u3 = *(const unsigned*)(ht8 + i3 * 128u + sub4);
    float g0 = gate_<LAYER>(r0) * scales[i0];
    float g1 = gate_<LAYER>(r1) * scales[i1];
    float g2 = gate_<LAYER>(r2) * scales[i2];
    float g3 = gate_<LAYER>(r3) * scales[i3];
    sgs += g0 + g1 + g2 + g3;
    ACC4(u0, g0) ACC4(u1, g1) ACC4(u2, g2) ACC4(u3, g3)
  }
  for (; j + 2 <= c; j += 2) {   // one pair
    uint2 r = csr[s + j + p];
    unsigned i0 = r.x & 0x1ffffu;
    unsigned u = *(const unsigned*)(ht8 + i0 * 128u + sub4);
    float g = gate_<LAYER>(r) * scales[i0];
    sgs += g;
    ACC4(u, g)
  }
  if (j < c) {                   // odd leftover: half 0 only
    uint2 r = csr[s + j];
    unsigned i0 = r.x & 0x1ffffu;
    unsigned u = *(const unsigned*)(ht8 + i0 * 128u + sub4);
    float g = (p == 0) ? gate_<LAYER>(r) * scales[i0] : 0.f;
    sgs += g;
    ACC4(u, g)
  }
  // combine the two halves (lanes l and l+32 cover identical columns)
  a0 += __shfl_xor(a0, 32); a1 += __shfl_xor(a1, 32);
  a2 += __shfl_xor(a2, 32); a3 += __shfl_xor(a3, 32);
  sgs += __shfl_xor(sgs, 32);
  float corr = 128.f * sgs;
  float inv = 1.f / (float)(c + 1);
  a0 = fmaxf((a0 - corr) * inv, 0.f);
  a1 = fmaxf((a1 - corr) * inv, 0.f);
  a2 = fmaxf((a2 - corr) * inv, 0.f);
  a3 = fmaxf((a3 - corr) * inv, 0.f);
  if (p == 0) {
    __half2 h01 = __floats2half2_rn(a0, a1);
    __half2 h23 = __floats2half2_rn(a2, a3);
    uint2 outw;
    outw.x = *(unsigned*)&h01;
    outw.y = *(unsigned*)&h23;
    *(uint2*)((char*)hout + (size_t)node * 256 + (size_t)sub * 8) = outw;
  }
}

// ---------------------------------------------------------------------------
extern "C" void kernel_launch(void* const* d_in, const int* in_sizes, int n_in,
                              void* d_out, int out_size, void* d_ws, size_t ws_size,
                              hipStream_t stream) {
  int ob = (out_size + 255) / 256;

  const float *x, *ea, *l1W, *l1b, *l2W, *l2b, *t1W, *t1b, *t2W, *t2b;
  const float *convW[3], *convb[3], *edgew[3];
  const int* ei;

  if (n_in == 20) {          // tuples flattened to separate entries
    x = (const float*)d_in[0]; ei = (const int*)d_in[1]; ea = (const float*)d_in[2];
    for (int l = 0; l < 3; l++) {
      convW[l] = (const float*)d_in[3 + l];
      convb[l] = (const float*)d_in[6 + l];
      edgew[l] = (const float*)d_in[9 + l];
    }
    l1W = (const float*)d_in[12]; l1b = (const float*)d_in[13];
    l2W = (const float*)d_in[14]; l2b = (const float*)d_in[15];
    t1W = (const float*)d_in[16]; t1b = (const float*)d_in[17];
    t2W = (const float*)d_in[18]; t2b = (const float*)d_in[19];
  } else if (n_in == 14) {   // each tuple is ONE concatenated buffer
    x = (const float*)d_in[0]; ei = (const int*)d_in[1]; ea = (const float*)d_in[2];
    const float* cw = (const float*)d_in[3];
    const float* cb = (const float*)d_in[4];
    const float* ew = (const float*)d_in[5];
    for (int l = 0; l < 3; l++) {
      convW[l] = cw + (size_t)l * 128 * 128;
      convb[l] = cb + (size_t)l * 128;
      edgew[l] = ew + l;
    }
    l1W = (const float*)d_in[6];  l1b = (const float*)d_in[7];
    l2W = (const float*)d_in[8];  l2b = (const float*)d_in[9];
    t1W = (const float*)d_in[10]; t1b = (const float*)d_in[11];
    t2W = (const float*)d_in[12]; t2b = (const float*)d_in[13];
  } else {
    sentinel_kernel<<<ob, 256, 0, stream>>>((float*)d_out, out_size,
                                            900.0f + (float)n_in);
    return;
  }

  int n = in_sizes[0] / 129;   // 100000
  int E = in_sizes[2];         // 1600000

  char* ws = (char*)d_ws;
  size_t off = 0;
  auto take = [&](size_t bytes) -> void* {
    void* p = ws + off;
    off = (off + bytes + 255) & ~(size_t)255;
    return p;
  };
  int*      flag    = (int*)take(256);
  uint2*    csr     = (uint2*)take((size_t)E * 8);           // 12.8 MB
  int*      counts8 = (int*)take((size_t)n * 8 * 4);         // 3.2 MB (8 parts)
  int*      starts  = (int*)take(((size_t)n + 1) * 4);
  int*      bsums   = (int*)take(512 * 4);
  float*    tbuf    = (float*)take((size_t)n * 4);
  float*    x0buf   = (float*)take((size_t)n * 4);
  int*      slot    = (int*)take((size_t)E * 4);             // 6.4 MB
  _Float16* h16     = (_Float16*)take((size_t)n * 128 * 2);  // 25.6 MB
  unsigned char* ht8 = (unsigned char*)take((size_t)n * 128); // 12.8 MB
  float*    scales  = (float*)take((size_t)n * 4);           // 400 KB

  if (off > ws_size) {
    sentinel_kernel<<<ob, 256, 0, stream>>>((float*)d_out, out_size,
                                            1000.0f + (float)(ws_size >> 20));
    return;
  }

  int eb = (E + 255) / 256;               // rank blocks
  int nb1 = (n + 1 + 255) / 256;          // scan1 blocks (392 <= 512)
  int zb8 = (n * 8 + 255) / 256;          // init blocks (8-way counts)
  int sb = (int)(((size_t)n * 128 + 255) / 256);  // slice blocks
  int sgrid = (eb + 3) / 4;               // scatter blocks
  int hgrid = (n + 63) / 64;              // head blocks

  init_kernel<<<zb8, 256, 0, stream>>>(ei, flag, counts8, n);
  rank_kernel<<<eb, 256, 0, stream>>>(ei, E, n, flag, slot, counts8);
  slice_kernel<<<sb, 256, 0, stream>>>(x, h16, x0buf, n);
  scan1_kernel<<<nb1, 256, 0, stream>>>(counts8, n, starts, bsums);
  scan2_kernel<<<1, 512, 0, stream>>>(bsums, nb1);
  scatter_head_kernel<<<sgrid + hgrid, 256, 0, stream>>>(
      ei, slot, starts, bsums, counts8, ea, E, n, flag,
      edgew[0], edgew[1], edgew[2], csr, sgrid,
      h16, x0buf, t1W, t1b, t2W, t2b, tbuf, 1, 0);

  int gemm_grid = min((n + 63) / 64, 1024);  // v22 setting (512 hurt)
  gemm_mfma_kernel<<<gemm_grid, 256, 0, stream>>>(h16, convW[0], convb[0], ht8, scales, n);
  agg_kernel<0><<<(n + 3) / 4, 256, 0, stream>>>(ht8, scales, csr, starts, bsums,
                                                 edgew[0], (__half2*)h16, n);
  gemm_mfma_kernel<<<gemm_grid, 256, 0, stream>>>(h16, convW[1], convb[1], ht8, scales, n);
  agg_kernel<1><<<(n + 3) / 4, 256, 0, stream>>>(ht8, scales, csr, starts, bsums,
                                                 edgew[1], (__half2*)h16, n);
  gemm_mfma_kernel<<<gemm_grid, 256, 0, stream>>>(h16, convW[2], convb[2], ht8, scales, n);
  agg_kernel<2><<<(n + 3) / 4, 256, 0, stream>>>(ht8, scales, csr, starts, bsums,
                                                 edgew[2], (__half2*)h16, n);

  // mlp: W1=l1W (129x64), h-rows 0..127, extra=t via row 128
  head_mfma_kernel<<<(n + 63) / 64, 256, 0, stream>>>(h16, tbuf, l1W, l1b, l2W, l2b,
                                                      (float*)d_out, n, 0, 128);
}

// Round 14
// 482.954 us; speedup vs baseline: 1.0996x; 1.0996x over previous
//
#include <hip/hip_runtime.h>
#include <hip/hip_fp16.h>
#include <math.h>

// ---------------------------------------------------------------------------
// DeepECCNet: 3-layer gated graph conv + t-gate + MLP head.
// v22: 499.6 us best. v25: 8-way partitioned atomics NULL (+31) -> atomic
//      wall is FABRIC-CENTRAL (4 probes: dense/padded/co-run/partitioned all
//      ~65-68us). Only escape: eliminate per-edge returning GLOBAL atomics.
// v26: atomic-free CSR build. Insight: agg sums per segment -> intra-node
//      order irrelevant -> no stability needed -> two-level bucket sort with
//      LDS-only atomics:
//        hist(391x391 block-bin matrix) -> scanrow -> binbase ->
//        reorder (bucket-ordered recs via LDS cursors, absolute positions) ->
//        fine (per-bucket 256-node CSR in 32KB L2-local span, emits starts).
//      Replaces init/rank/scan1/scan2/scatter (~120us) with ~45us. bsums
//      gone from agg (starts now absolute). tnet head standalone again.
//      Predict total ~445-465, absmax unchanged.
// ---------------------------------------------------------------------------

typedef _Float16 f16x8 __attribute__((ext_vector_type(8)));
typedef float f32x4 __attribute__((ext_vector_type(4)));

#define EPB 4096  // edges per block in phase A

__device__ __forceinline__ float sigmoidf_(float v) { return 1.f / (1.f + expf(-v)); }

__global__ void sentinel_kernel(float* __restrict__ out, int n, float val) {
  int i = blockIdx.x * 256 + threadIdx.x;
  if (i < n) out[i] = val;
}

// ---- flag: detect int64 edge_index -----------------------------------------
__global__ void flag_kernel(const int* __restrict__ ei, int* __restrict__ flag) {
  if (threadIdx.x == 0 && blockIdx.x == 0) {
    int all0 = 1;
    for (int k = 1; k < 512; k += 2) {
      if (ei[k] != 0) { all0 = 0; break; }
    }
    *flag = all0;
  }
}

// ---- hist: per-block LDS histogram over coarse bins (t>>8) -----------------
__global__ __launch_bounds__(256) void hist_kernel(const int* __restrict__ ei,
    int E, int n, const int* __restrict__ flag, int* __restrict__ histA,
    int nblocksA, int NB) {
  __shared__ int hl[512];
  for (int i = threadIdx.x; i < NB; i += 256) hl[i] = 0;
  __syncthreads();
  int f64 = *flag;
  const long long* e64 = (const long long*)ei;
  int base = blockIdx.x * EPB;
  int end = min(base + EPB, E);
  for (int e = base + threadIdx.x; e < end; e += 256) {
    int t = f64 ? (int)e64[(size_t)E + e] : ei[(size_t)E + e];
    if ((unsigned)t < (unsigned)n) atomicAdd(&hl[t >> 8], 1);
  }
  __syncthreads();
  for (int i = threadIdx.x; i < NB; i += 256)
    histA[(size_t)i * nblocksA + blockIdx.x] = hl[i];
}

// ---- scanrow: exclusive scan each bin's row across blocks (carry chunks) ---
__global__ __launch_bounds__(256) void scanrow_kernel(int* __restrict__ histA,
    int nblocksA, int* __restrict__ binTotal) {
  __shared__ int tmp[256];
  int bin = blockIdx.x;
  int* row = histA + (size_t)bin * nblocksA;
  int carry = 0;
  for (int c0 = 0; c0 < nblocksA; c0 += 256) {
    int i = c0 + threadIdx.x;
    int v = (i < nblocksA) ? row[i] : 0;
    tmp[threadIdx.x] = v;
    __syncthreads();
    for (int off = 1; off < 256; off <<= 1) {
      int t = (threadIdx.x >= (unsigned)off) ? tmp[threadIdx.x - off] : 0;
      __syncthreads();
      tmp[threadIdx.x] += t;
      __syncthreads();
    }
    if (i < nblocksA) row[i] = carry + tmp[threadIdx.x] - v;  // exclusive
    carry += tmp[255];
    __syncthreads();
  }
  if (threadIdx.x == 0) binTotal[bin] = carry;
}

// ---- binbase: exclusive scan of bin totals; writes starts[n] = total -------
__global__ void binbase_kernel(const int* __restrict__ binTotal, int NB,
                               int* __restrict__ binBase, int* __restrict__ starts,
                               int n) {
  __shared__ int tmp[512];
  int v = (threadIdx.x < (unsigned)NB) ? binTotal[threadIdx.x] : 0;
  tmp[threadIdx.x] = v;
  __syncthreads();
  for (int off = 1; off < 512; off <<= 1) {
    int t = (threadIdx.x >= (unsigned)off) ? tmp[threadIdx.x - off] : 0;
    __syncthreads();
    tmp[threadIdx.x] += t;
    __syncthreads();
  }
  if (threadIdx.x < (unsigned)NB) binBase[threadIdx.x] = tmp[threadIdx.x] - v;
  if (threadIdx.x == (unsigned)(NB - 1)) {
    binBase[NB] = tmp[threadIdx.x];
    starts[n] = tmp[threadIdx.x];
  }
}

// ---- reorder: place {rec, t&255} bucket-ordered via LDS cursors ------------
__global__ __launch_bounds__(256) void reorder_kernel(const int* __restrict__ ei,
    const float* __restrict__ ea, int E, int n, const int* __restrict__ flag,
    const int* __restrict__ histA, int nblocksA, const int* __restrict__ binBase,
    const float* __restrict__ w0p, const float* __restrict__ w1p,
    const float* __restrict__ w2p, uint2* __restrict__ brec,
    unsigned char* __restrict__ bkey, int NB) {
  __shared__ int cur[512];
  for (int i = threadIdx.x; i < NB; i += 256)
    cur[i] = binBase[i] + histA[(size_t)i * nblocksA + blockIdx.x];
  __syncthreads();
  float w0 = w0p[0], w1 = w1p[0], w2 = w2p[0];
  int f64 = *flag;
  const long long* e64 = (const long long*)ei;
  int base = blockIdx.x * EPB;
  int end = min(base + EPB, E);
  for (int e = base + threadIdx.x; e < end; e += 256) {
    int s, t;
    if (f64) { s = (int)e64[e]; t = (int)e64[(size_t)E + e]; }
    else     { s = ei[e];       t = ei[(size_t)E + e]; }
    if ((unsigned)t < (unsigned)n) {
      int pos = atomicAdd(&cur[t >> 8], 1);   // absolute position
      float a = ea[e];
      unsigned sn = (unsigned)min(max(s, 0), min(n - 1, 0x1ffff));
      unsigned g0 = (unsigned)__float2uint_rn(sigmoidf_(a * w0) * 32767.f);
      unsigned g1 = (unsigned)__float2uint_rn(sigmoidf_(a * w1) * 32767.f);
      unsigned g2 = (unsigned)__float2uint_rn(sigmoidf_(a * w2) * 32767.f);
      brec[pos] = make_uint2(sn | (g0 << 17), g1 | (g2 << 15));
      bkey[pos] = (unsigned char)(t & 255);
    }
  }
}

// ---- fine: per-bucket (256 nodes) CSR build in L2-local span ---------------
__global__ __launch_bounds__(256) void fine_kernel(const uint2* __restrict__ brec,
    const unsigned char* __restrict__ bkey, const int* __restrict__ binBase,
    int n, uint2* __restrict__ csr, int* __restrict__ starts) {
  __shared__ int cnt[256];
  __shared__ int offs[256];
  __shared__ int tmp[256];
  int bin = blockIdx.x;
  int b0 = binBase[bin], b1 = binBase[bin + 1];
  cnt[threadIdx.x] = 0;
  __syncthreads();
  for (int p = b0 + threadIdx.x; p < b1; p += 256)
    atomicAdd(&cnt[bkey[p]], 1);
  __syncthreads();
  int v = cnt[threadIdx.x];
  tmp[threadIdx.x] = v;
  __syncthreads();
  for (int off = 1; off < 256; off <<= 1) {
    int t = (threadIdx.x >= (unsigned)off) ? tmp[threadIdx.x - off] : 0;
    __syncthreads();
    tmp[threadIdx.x] += t;
    __syncthreads();
  }
  offs[threadIdx.x] = tmp[threadIdx.x] - v;  // exclusive within bucket
  int node = bin * 256 + threadIdx.x;
  if (node < n) starts[node] = b0 + offs[threadIdx.x];
  __syncthreads();
  cnt[threadIdx.x] = 0;  // reuse as cursors
  __syncthreads();
  for (int p = b0 + threadIdx.x; p < b1; p += 256) {
    int k = bkey[p];
    int l = atomicAdd(&cnt[k], 1);
    csr[b0 + offs[k] + l] = brec[p];
  }
}

// ---- h0 = fp16(x[:, 1:]); x0 = x[:, 0] -------------------------------------
__global__ void slice_kernel(const float* __restrict__ x, _Float16* __restrict__ h,
                             float* __restrict__ x0, int n) {
  int idx = blockIdx.x * blockDim.x + threadIdx.x;
  if (idx < n * 128) {
    int node = idx >> 7;
    int k = idx & 127;
    h[idx] = (_Float16)x[(size_t)node * 129 + 1 + k];
  }
  if (idx < n) x0[idx] = x[(size_t)idx * 129];
}

// ---- MFMA head: out = sigmoid( relu(h@W1[hrow0:+128] + extra*W1[xrow] + b1)
//      @ w2 + b2 ) -----------------------------------------------------------
__global__ __launch_bounds__(256) void head_mfma_kernel(const _Float16* __restrict__ h,
    const float* __restrict__ extra, const float* __restrict__ W1,
    const float* __restrict__ b1, const float* __restrict__ w2,
    const float* __restrict__ b2, float* __restrict__ out, int n,
    int hrow0, int xrow) {
  __shared__ __align__(16) _Float16 sB[4 * 4 * 64 * 8];  // 16 KB, B-frag order
  __shared__ float sWx[64], sB1[64], sW2[64];
  for (int idx = threadIdx.x; idx < 8192; idx += 256) {
    int k = idx >> 6, col = idx & 63;
    float w = W1[(size_t)(hrow0 + k) * 64 + col];
    int ks = k >> 5, quad = (k >> 3) & 3, j = k & 7;
    int nt = col >> 4, cl = col & 15;
    sB[(((ks * 4 + nt) * 64) + quad * 16 + cl) * 8 + j] = (_Float16)w;
  }
  if (threadIdx.x < 64) {
    sWx[threadIdx.x] = W1[(size_t)xrow * 64 + threadIdx.x];
    sB1[threadIdx.x] = b1[threadIdx.x];
    sW2[threadIdx.x] = w2[threadIdx.x];
  }
  __syncthreads();
  int wv = threadIdx.x >> 6, lane = threadIdx.x & 63;
  int quad = lane >> 4, l15 = lane & 15;
  int n0 = (blockIdx.x * 4 + wv) * 16;
  if (n0 >= n) return;
  int node_a = min(n0 + l15, n - 1);
  const _Float16* hrow = h + (size_t)node_a * 128 + quad * 8;

  f32x4 acc[4];
#pragma unroll
  for (int t = 0; t < 4; t++) acc[t] = (f32x4){0.f, 0.f, 0.f, 0.f};
  for (int ks = 0; ks < 4; ks++) {
    f16x8 afrag = *(const f16x8*)(hrow + ks * 32);
    const f16x8* bp = (const f16x8*)sB;
#pragma unroll
    for (int t = 0; t < 4; t++) {
      f16x8 bfrag = bp[(ks * 4 + t) * 64 + lane];
      acc[t] = __builtin_amdgcn_mfma_f32_16x16x32_f16(afrag, bfrag, acc[t], 0, 0, 0);
    }
  }
  float b2v = b2[0];
  float xv[4], part[4] = {0.f, 0.f, 0.f, 0.f};
#pragma unroll
  for (int r = 0; r < 4; r++) xv[r] = extra[min(n0 + quad * 4 + r, n - 1)];
#pragma unroll
  for (int t = 0; t < 4; t++) {
    int col = t * 16 + l15;
    float wx = sWx[col], bb = sB1[col], w2v = sW2[col];
#pragma unroll
    for (int r = 0; r < 4; r++) {
      float u = fmaxf(acc[t][r] + xv[r] * wx + bb, 0.f);
      part[r] += u * w2v;
    }
  }
#pragma unroll
  for (int r = 0; r < 4; r++) {
    float p = part[r];
    p += __shfl_xor(p, 1); p += __shfl_xor(p, 2);
    p += __shfl_xor(p, 4); p += __shfl_xor(p, 8);
    int node = n0 + quad * 4 + r;
    if (l15 == 0 && node < n) out[node] = sigmoidf_(p + b2v);
  }
}

// ---- MFMA GEMM: ht8/scales = rowquant(h16 @ W + b) -------------------------
__global__ __launch_bounds__(256) void gemm_mfma_kernel(const _Float16* __restrict__ h,
    const float* __restrict__ Wg, const float* __restrict__ b,
    unsigned char* __restrict__ out8, float* __restrict__ scales, int n) {
  __shared__ __align__(16) _Float16 sB[4 * 8 * 64 * 8];  // 32 KB
  for (int i = threadIdx.x; i < 4096; i += 256) {  // i = float4 index over W
    int k = i >> 5;
    int n4 = (i & 31) * 4;
    float4 w4 = ((const float4*)Wg)[i];
    int ks = k >> 5, quad = (k >> 3) & 3, j = k & 7;
#pragma unroll
    for (int c = 0; c < 4; c++) {
      int col = n4 + c;
      int nt = col >> 4, cl = col & 15;
      sB[(((ks * 8 + nt) * 64) + quad * 16 + cl) * 8 + j] =
          (_Float16)((const float*)&w4)[c];
    }
  }
  __syncthreads();
  int wv = threadIdx.x >> 6, lane = threadIdx.x & 63;
  int quad = lane >> 4, l15 = lane & 15;
  int tiles = (n + 63) >> 6;
  for (int tile = blockIdx.x; tile < tiles; tile += gridDim.x) {
    int n0 = (tile * 4 + wv) * 16;
    if (n0 >= n) continue;
    int node_a = min(n0 + l15, n - 1);
    const _Float16* hrow = h + (size_t)node_a * 128 + quad * 8;

    f32x4 acc[8];
#pragma unroll
    for (int t = 0; t < 8; t++) acc[t] = (f32x4){0.f, 0.f, 0.f, 0.f};

    for (int ks = 0; ks < 4; ks++) {
      f16x8 afrag = *(const f16x8*)(hrow + ks * 32);
      const f16x8* bp = (const f16x8*)(sB + ks * 8 * 64 * 8);
#pragma unroll
      for (int t = 0; t < 8; t++) {
        f16x8 bfrag = bp[t * 64 + lane];
        acc[t] = __builtin_amdgcn_mfma_f32_16x16x32_f16(afrag, bfrag, acc[t], 0, 0, 0);
      }
    }
#pragma unroll
    for (int t = 0; t < 8; t++) {
      float bias = b[t * 16 + l15];
#pragma unroll
      for (int r = 0; r < 4; r++) acc[t][r] += bias;
    }
    float mx[4] = {0.f, 0.f, 0.f, 0.f};
#pragma unroll
    for (int t = 0; t < 8; t++)
#pragma unroll
      for (int r = 0; r < 4; r++) mx[r] = fmaxf(mx[r], fabsf(acc[t][r]));
#pragma unroll
    for (int m = 1; m <= 8; m <<= 1) {
#pragma unroll
      for (int r = 0; r < 4; r++) mx[r] = fmaxf(mx[r], __shfl_xor(mx[r], m));
    }
#pragma unroll
    for (int r = 0; r < 4; r++) {
      int node = n0 + quad * 4 + r;
      if (node >= n) continue;
      float inv = (mx[r] > 0.f) ? 127.f / mx[r] : 0.f;
      if (l15 == 0) scales[node] = mx[r] * (1.f / 127.f);
#pragma unroll
      for (int t = 0; t < 8; t++) {
        int u = (int)rintf(acc[t][r] * inv) + 128;
        u = min(max(u, 0), 255);
        out8[(size_t)node * 128 + t * 16 + l15] = (unsigned char)u;
      }
    }
  }
}

// ---- aggregation: int8 rows, edge-pair halves, absolute starts -------------
template <int LAYER>
__device__ __forceinline__ float gate_(uint2 r) {
  const float inv = 1.f / 32767.f;
  if (LAYER == 0) return (float)(r.x >> 17) * inv;
  if (LAYER == 1) return (float)(r.y & 0x7fffu) * inv;
  return (float)(r.y >> 15) * inv;
}

#define ACC4(u, g)                                   \
  a0 += (float)((u) & 0xffu) * (g);                  \
  a1 += (float)(((u) >> 8) & 0xffu) * (g);           \
  a2 += (float)(((u) >> 16) & 0xffu) * (g);          \
  a3 += (float)((u) >> 24) * (g);

template <int LAYER>
__global__ __launch_bounds__(256) void agg_kernel(const unsigned char* __restrict__ ht8,
    const float* __restrict__ scales, const uint2* __restrict__ csr,
    const int* __restrict__ starts, const float* __restrict__ wp,
    __half2* __restrict__ hout, int n) {
  int wv = threadIdx.x >> 6, lane = threadIdx.x & 63;
  int node = blockIdx.x * 4 + wv;
  if (node >= n) return;
  int s = starts[node];
  int c = starts[node + 1] - s;
  float gs = sigmoidf_(wp[0]);
  int sub = lane & 31, p = lane >> 5;
  unsigned sub4 = (unsigned)sub * 4u;

  unsigned su = *(const unsigned*)(ht8 + (unsigned)node * 128u + sub4);
  float gsc = (p == 0) ? gs * scales[node] : 0.f;
  float sgs = gsc;
  float a0 = 0.f, a1 = 0.f, a2 = 0.f, a3 = 0.f;
  ACC4(su, gsc)

  int j = 0;
  for (; j + 16 <= c; j += 16) {
    uint2 r0 = csr[s + j + 0 + p],  r1 = csr[s + j + 2 + p];
    uint2 r2 = csr[s + j + 4 + p],  r3 = csr[s + j + 6 + p];
    uint2 r4 = csr[s + j + 8 + p],  r5 = csr[s + j + 10 + p];
    uint2 r6 = csr[s + j + 12 + p], r7 = csr[s + j + 14 + p];
    unsigned i0 = r0.x & 0x1ffffu, i1 = r1.x & 0x1ffffu;
    unsigned i2 = r2.x & 0x1ffffu, i3 = r3.x & 0x1ffffu;
    unsigned i4 = r4.x & 0x1ffffu, i5 = r5.x & 0x1ffffu;
    unsigned i6 = r6.x & 0x1ffffu, i7 = r7.x & 0x1ffffu;
    unsigned u0 = *(const unsigned*)(ht8 + i0 * 128u + sub4);
    unsigned u1 = *(const unsigned*)(ht8 + i1 * 128u + sub4);
    unsigned u2 = *(const unsigned*)(ht8 + i2 * 128u + sub4);
    unsigned u3 = *(const unsigned*)(ht8 + i3 * 128u + sub4);
    unsigned u4 = *(const unsigned*)(ht8 + i4 * 128u + sub4);
    unsigned u5 = *(const unsigned*)(ht8 + i5 * 128u + sub4);
    unsigned u6 = *(const unsigned*)(ht8 + i6 * 128u + sub4);
    unsigned u7 = *(const unsigned*)(ht8 + i7 * 128u + sub4);
    float g0 = gate_<LAYER>(r0) * scales[i0];
    float g1 = gate_<LAYER>(r1) * scales[i1];
    float g2 = gate_<LAYER>(r2) * scales[i2];
    float g3 = gate_<LAYER>(r3) * scales[i3];
    float g4 = gate_<LAYER>(r4) * scales[i4];
    float g5 = gate_<LAYER>(r5) * scales[i5];
    float g6 = gate_<LAYER>(r6) * scales[i6];
    float g7 = gate_<LAYER>(r7) * scales[i7];
    sgs += g0 + g1 + g2 + g3 + g4 + g5 + g6 + g7;
    ACC4(u0, g0) ACC4(u1, g1) ACC4(u2, g2) ACC4(u3, g3)
    ACC4(u4, g4) ACC4(u5, g5) ACC4(u6, g6) ACC4(u7, g7)
  }
  for (; j + 8 <= c; j += 8) {
    uint2 r0 = csr[s + j + 0 + p], r1 = csr[s + j + 2 + p];
    uint2 r2 = csr[s + j + 4 + p], r3 = csr[s + j + 6 + p];
    unsigned i0 = r0.x & 0x1ffffu, i1 = r1.x & 0x1ffffu;
    unsigned i2 = r2.x & 0x1ffffu, i3 = r3.x & 0x1ffffu;
    unsigned u0 = *(const unsigned*)(ht8 + i0 * 128u + sub4);
    unsigned u1 = *(const unsigned*)(ht8 + i1 * 128u + sub4);
    unsigned u2 = *(const unsigned*)(ht8 + i2 * 128u + sub4);
    unsigned u3 = *(const unsigned*)(ht8 + i3 * 128u + sub4);
    float g0 = gate_<LAYER>(r0) * scales[i0];
    float g1 = gate_<LAYER>(r1) * scales[i1];
    float g2 = gate_<LAYER>(r2) * scales[i2];
    float g3 = gate_<LAYER>(r3) * scales[i3];
    sgs += g0 + g1 + g2 + g3;
    ACC4(u0, g0) ACC4(u1, g1) ACC4(u2, g2) ACC4(u3, g3)
  }
  for (; j + 2 <= c; j += 2) {
    uint2 r = csr[s + j + p];
    unsigned i0 = r.x & 0x1ffffu;
    unsigned u = *(const unsigned*)(ht8 + i0 * 128u + sub4);
    float g = gate_<LAYER>(r) * scales[i0];
    sgs += g;
    ACC4(u, g)
  }
  if (j < c) {
    uint2 r = csr[s + j];
    unsigned i0 = r.x & 0x1ffffu;
    unsigned u = *(const unsigned*)(ht8 + i0 * 128u + sub4);
    float g = (p == 0) ? gate_<LAYER>(r) * scales[i0] : 0.f;
    sgs += g;
    ACC4(u, g)
  }
  a0 += __shfl_xor(a0, 32); a1 += __shfl_xor(a1, 32);
  a2 += __shfl_xor(a2, 32); a3 += __shfl_xor(a3, 32);
  sgs += __shfl_xor(sgs, 32);
  float corr = 128.f * sgs;
  float inv = 1.f / (float)(c + 1);
  a0 = fmaxf((a0 - corr) * inv, 0.f);
  a1 = fmaxf((a1 - corr) * inv, 0.f);
  a2 = fmaxf((a2 - corr) * inv, 0.f);
  a3 = fmaxf((a3 - corr) * inv, 0.f);
  if (p == 0) {
    __half2 h01 = __floats2half2_rn(a0, a1);
    __half2 h23 = __floats2half2_rn(a2, a3);
    uint2 outw;
    outw.x = *(unsigned*)&h01;
    outw.y = *(unsigned*)&h23;
    *(uint2*)((char*)hout + (size_t)node * 256 + (size_t)sub * 8) = outw;
  }
}

// ---------------------------------------------------------------------------
extern "C" void kernel_launch(void* const* d_in, const int* in_sizes, int n_in,
                              void* d_out, int out_size, void* d_ws, size_t ws_size,
                              hipStream_t stream) {
  int ob = (out_size + 255) / 256;

  const float *x, *ea, *l1W, *l1b, *l2W, *l2b, *t1W, *t1b, *t2W, *t2b;
  const float *convW[3], *convb[3], *edgew[3];
  const int* ei;

  if (n_in == 20) {          // tuples flattened to separate entries
    x = (const float*)d_in[0]; ei = (const int*)d_in[1]; ea = (const float*)d_in[2];
    for (int l = 0; l < 3; l++) {
      convW[l] = (const float*)d_in[3 + l];
      convb[l] = (const float*)d_in[6 + l];
      edgew[l] = (const float*)d_in[9 + l];
    }
    l1W = (const float*)d_in[12]; l1b = (const float*)d_in[13];
    l2W = (const float*)d_in[14]; l2b = (const float*)d_in[15];
    t1W = (const float*)d_in[16]; t1b = (const float*)d_in[17];
    t2W = (const float*)d_in[18]; t2b = (const float*)d_in[19];
  } else if (n_in == 14) {   // each tuple is ONE concatenated buffer
    x = (const float*)d_in[0]; ei = (const int*)d_in[1]; ea = (const float*)d_in[2];
    const float* cw = (const float*)d_in[3];
    const float* cb = (const float*)d_in[4];
    const float* ew = (const float*)d_in[5];
    for (int l = 0; l < 3; l++) {
      convW[l] = cw + (size_t)l * 128 * 128;
      convb[l] = cb + (size_t)l * 128;
      edgew[l] = ew + l;
    }
    l1W = (const float*)d_in[6];  l1b = (const float*)d_in[7];
    l2W = (const float*)d_in[8];  l2b = (const float*)d_in[9];
    t1W = (const float*)d_in[10]; t1b = (const float*)d_in[11];
    t2W = (const float*)d_in[12]; t2b = (const float*)d_in[13];
  } else {
    sentinel_kernel<<<ob, 256, 0, stream>>>((float*)d_out, out_size,
                                            900.0f + (float)n_in);
    return;
  }

  int n = in_sizes[0] / 129;   // 100000
  int E = in_sizes[2];         // 1600000

  int nblocksA = (E + EPB - 1) / EPB;  // 391 (must be <= 1024)
  int NB = (n + 255) >> 8;             // 391 coarse bins (must be <= 512)

  char* ws = (char*)d_ws;
  size_t off = 0;
  auto take = [&](size_t bytes) -> void* {
    void* p = ws + off;
    off = (off + bytes + 255) & ~(size_t)255;
    return p;
  };
  int*      flag    = (int*)take(256);
  int*      histA   = (int*)take((size_t)NB * nblocksA * 4);  // ~612 KB
  int*      binTot  = (int*)take((size_t)NB * 4);
  int*      binBase = (int*)take(((size_t)NB + 1) * 4);
  int*      starts  = (int*)take(((size_t)n + 1) * 4);
  uint2*    brec    = (uint2*)take((size_t)E * 8);            // 12.8 MB
  unsigned char* bkey = (unsigned char*)take((size_t)E);      // 1.6 MB
  uint2*    csr     = (uint2*)take((size_t)E * 8);            // 12.8 MB
  float*    tbuf    = (float*)take((size_t)n * 4);
  float*    x0buf   = (float*)take((size_t)n * 4);
  _Float16* h16     = (_Float16*)take((size_t)n * 128 * 2);   // 25.6 MB
  unsigned char* ht8 = (unsigned char*)take((size_t)n * 128); // 12.8 MB
  float*    scales  = (float*)take((size_t)n * 4);            // 400 KB

  if (off > ws_size || nblocksA > 1024 || NB > 512) {
    sentinel_kernel<<<ob, 256, 0, stream>>>((float*)d_out, out_size,
                                            1000.0f + (float)(ws_size >> 20));
    return;
  }

  int sb = (int)(((size_t)n * 128 + 255) / 256);  // slice blocks
  int hgrid = (n + 63) / 64;                      // head blocks

  flag_kernel<<<1, 64, 0, stream>>>(ei, flag);
  hist_kernel<<<nblocksA, 256, 0, stream>>>(ei, E, n, flag, histA, nblocksA, NB);
  scanrow_kernel<<<NB, 256, 0, stream>>>(histA, nblocksA, binTot);
  binbase_kernel<<<1, 512, 0, stream>>>(binTot, NB, binBase, starts, n);
  reorder_kernel<<<nblocksA, 256, 0, stream>>>(ei, ea, E, n, flag, histA, nblocksA,
                                               binBase, edgew[0], edgew[1], edgew[2],
                                               brec, bkey, NB);
  fine_kernel<<<NB, 256, 0, stream>>>(brec, bkey, binBase, n, csr, starts);

  slice_kernel<<<sb, 256, 0, stream>>>(x, h16, x0buf, n);
  // tnet: W1=t1W (129x64), h-rows 1..128, extra=x0 via row 0
  head_mfma_kernel<<<hgrid, 256, 0, stream>>>(h16, x0buf, t1W, t1b, t2W, t2b,
                                              tbuf, n, 1, 0);

  int gemm_grid = min((n + 63) / 64, 1024);
  gemm_mfma_kernel<<<gemm_grid, 256, 0, stream>>>(h16, convW[0], convb[0], ht8, scales, n);
  agg_kernel<0><<<(n + 3) / 4, 256, 0, stream>>>(ht8, scales, csr, starts,
                                                 edgew[0], (__half2*)h16, n);
  gemm_mfma_kernel<<<gemm_grid, 256, 0, stream>>>(h16, convW[1], convb[1], ht8, scales, n);
  agg_kernel<1><<<(n + 3) / 4, 256, 0, stream>>>(ht8, scales, csr, starts,
                                                 edgew[1], (__half2*)h16, n);
  gemm_mfma_kernel<<<gemm_grid, 256, 0, stream>>>(h16, convW[2], convb[2], ht8, scales, n);
  agg_kernel<2><<<(n + 3) / 4, 256, 0, stream>>>(ht8, scales, csr, starts,
                                                 edgew[2], (__half2*)h16, n);

  // mlp: W1=l1W (129x64), h-rows 0..127, extra=t via row 128
  head_mfma_kernel<<<hgrid, 256, 0, stream>>>(h16, tbuf, l1W, l1b, l2W, l2b,
                                              (float*)d_out, n, 0, 128);
}

// Round 15
// 476.292 us; speedup vs baseline: 1.1149x; 1.0140x over previous
//
#include <hip/hip_runtime.h>
#include <hip/hip_fp16.h>
#include <math.h>

// ---------------------------------------------------------------------------
// DeepECCNet: 3-layer gated graph conv + t-gate + MLP head.
// v26: atomic-free CSR build (hist/scanrow/binbase/reorder/fine) -> 483.0us
//      best. rank's 67us fabric-atomic wall eliminated. New top: reorder
//      61us @ 13% occupancy = GRID-STARVED (391 blocks = 1.5/CU; random-
//      write latency unhidden). agg 60.8 @ VALU 75%, FETCH 93.6MB (bucket
//      order improved locality; now VALU-leaning - later target).
// v27: EPB 4096 -> 1024 (one change). nblocksA 391 -> 1563 = 6.1 blocks/CU
//      for hist+reorder. histA 2.4MB. Predict reorder 61 -> ~25-30, total
//      ~445-455. If reorder >=50 at high occ -> RFO-bound -> LDS batch next.
// ---------------------------------------------------------------------------

typedef _Float16 f16x8 __attribute__((ext_vector_type(8)));
typedef float f32x4 __attribute__((ext_vector_type(4)));

#define EPB 1024  // edges per block in phase A (v27: was 4096)

__device__ __forceinline__ float sigmoidf_(float v) { return 1.f / (1.f + expf(-v)); }

__global__ void sentinel_kernel(float* __restrict__ out, int n, float val) {
  int i = blockIdx.x * 256 + threadIdx.x;
  if (i < n) out[i] = val;
}

// ---- flag: detect int64 edge_index -----------------------------------------
__global__ void flag_kernel(const int* __restrict__ ei, int* __restrict__ flag) {
  if (threadIdx.x == 0 && blockIdx.x == 0) {
    int all0 = 1;
    for (int k = 1; k < 512; k += 2) {
      if (ei[k] != 0) { all0 = 0; break; }
    }
    *flag = all0;
  }
}

// ---- hist: per-block LDS histogram over coarse bins (t>>8) -----------------
__global__ __launch_bounds__(256) void hist_kernel(const int* __restrict__ ei,
    int E, int n, const int* __restrict__ flag, int* __restrict__ histA,
    int nblocksA, int NB) {
  __shared__ int hl[512];
  for (int i = threadIdx.x; i < NB; i += 256) hl[i] = 0;
  __syncthreads();
  int f64 = *flag;
  const long long* e64 = (const long long*)ei;
  int base = blockIdx.x * EPB;
  int end = min(base + EPB, E);
  for (int e = base + threadIdx.x; e < end; e += 256) {
    int t = f64 ? (int)e64[(size_t)E + e] : ei[(size_t)E + e];
    if ((unsigned)t < (unsigned)n) atomicAdd(&hl[t >> 8], 1);
  }
  __syncthreads();
  for (int i = threadIdx.x; i < NB; i += 256)
    histA[(size_t)i * nblocksA + blockIdx.x] = hl[i];
}

// ---- scanrow: exclusive scan each bin's row across blocks (carry chunks) ---
__global__ __launch_bounds__(256) void scanrow_kernel(int* __restrict__ histA,
    int nblocksA, int* __restrict__ binTotal) {
  __shared__ int tmp[256];
  int bin = blockIdx.x;
  int* row = histA + (size_t)bin * nblocksA;
  int carry = 0;
  for (int c0 = 0; c0 < nblocksA; c0 += 256) {
    int i = c0 + threadIdx.x;
    int v = (i < nblocksA) ? row[i] : 0;
    tmp[threadIdx.x] = v;
    __syncthreads();
    for (int off = 1; off < 256; off <<= 1) {
      int t = (threadIdx.x >= (unsigned)off) ? tmp[threadIdx.x - off] : 0;
      __syncthreads();
      tmp[threadIdx.x] += t;
      __syncthreads();
    }
    if (i < nblocksA) row[i] = carry + tmp[threadIdx.x] - v;  // exclusive
    carry += tmp[255];
    __syncthreads();
  }
  if (threadIdx.x == 0) binTotal[bin] = carry;
}

// ---- binbase: exclusive scan of bin totals; writes starts[n] = total -------
__global__ void binbase_kernel(const int* __restrict__ binTotal, int NB,
                               int* __restrict__ binBase, int* __restrict__ starts,
                               int n) {
  __shared__ int tmp[512];
  int v = (threadIdx.x < (unsigned)NB) ? binTotal[threadIdx.x] : 0;
  tmp[threadIdx.x] = v;
  __syncthreads();
  for (int off = 1; off < 512; off <<= 1) {
    int t = (threadIdx.x >= (unsigned)off) ? tmp[threadIdx.x - off] : 0;
    __syncthreads();
    tmp[threadIdx.x] += t;
    __syncthreads();
  }
  if (threadIdx.x < (unsigned)NB) binBase[threadIdx.x] = tmp[threadIdx.x] - v;
  if (threadIdx.x == (unsigned)(NB - 1)) {
    binBase[NB] = tmp[threadIdx.x];
    starts[n] = tmp[threadIdx.x];
  }
}

// ---- reorder: place {rec, t&255} bucket-ordered via LDS cursors ------------
__global__ __launch_bounds__(256) void reorder_kernel(const int* __restrict__ ei,
    const float* __restrict__ ea, int E, int n, const int* __restrict__ flag,
    const int* __restrict__ histA, int nblocksA, const int* __restrict__ binBase,
    const float* __restrict__ w0p, const float* __restrict__ w1p,
    const float* __restrict__ w2p, uint2* __restrict__ brec,
    unsigned char* __restrict__ bkey, int NB) {
  __shared__ int cur[512];
  for (int i = threadIdx.x; i < NB; i += 256)
    cur[i] = binBase[i] + histA[(size_t)i * nblocksA + blockIdx.x];
  __syncthreads();
  float w0 = w0p[0], w1 = w1p[0], w2 = w2p[0];
  int f64 = *flag;
  const long long* e64 = (const long long*)ei;
  int base = blockIdx.x * EPB;
  int end = min(base + EPB, E);
  for (int e = base + threadIdx.x; e < end; e += 256) {
    int s, t;
    if (f64) { s = (int)e64[e]; t = (int)e64[(size_t)E + e]; }
    else     { s = ei[e];       t = ei[(size_t)E + e]; }
    if ((unsigned)t < (unsigned)n) {
      int pos = atomicAdd(&cur[t >> 8], 1);   // absolute position
      float a = ea[e];
      unsigned sn = (unsigned)min(max(s, 0), min(n - 1, 0x1ffff));
      unsigned g0 = (unsigned)__float2uint_rn(sigmoidf_(a * w0) * 32767.f);
      unsigned g1 = (unsigned)__float2uint_rn(sigmoidf_(a * w1) * 32767.f);
      unsigned g2 = (unsigned)__float2uint_rn(sigmoidf_(a * w2) * 32767.f);
      brec[pos] = make_uint2(sn | (g0 << 17), g1 | (g2 << 15));
      bkey[pos] = (unsigned char)(t & 255);
    }
  }
}

// ---- fine: per-bucket (256 nodes) CSR build in L2-local span ---------------
__global__ __launch_bounds__(256) void fine_kernel(const uint2* __restrict__ brec,
    const unsigned char* __restrict__ bkey, const int* __restrict__ binBase,
    int n, uint2* __restrict__ csr, int* __restrict__ starts) {
  __shared__ int cnt[256];
  __shared__ int offs[256];
  __shared__ int tmp[256];
  int bin = blockIdx.x;
  int b0 = binBase[bin], b1 = binBase[bin + 1];
  cnt[threadIdx.x] = 0;
  __syncthreads();
  for (int p = b0 + threadIdx.x; p < b1; p += 256)
    atomicAdd(&cnt[bkey[p]], 1);
  __syncthreads();
  int v = cnt[threadIdx.x];
  tmp[threadIdx.x] = v;
  __syncthreads();
  for (int off = 1; off < 256; off <<= 1) {
    int t = (threadIdx.x >= (unsigned)off) ? tmp[threadIdx.x - off] : 0;
    __syncthreads();
    tmp[threadIdx.x] += t;
    __syncthreads();
  }
  offs[threadIdx.x] = tmp[threadIdx.x] - v;  // exclusive within bucket
  int node = bin * 256 + threadIdx.x;
  if (node < n) starts[node] = b0 + offs[threadIdx.x];
  __syncthreads();
  cnt[threadIdx.x] = 0;  // reuse as cursors
  __syncthreads();
  for (int p = b0 + threadIdx.x; p < b1; p += 256) {
    int k = bkey[p];
    int l = atomicAdd(&cnt[k], 1);
    csr[b0 + offs[k] + l] = brec[p];
  }
}

// ---- h0 = fp16(x[:, 1:]); x0 = x[:, 0] -------------------------------------
__global__ void slice_kernel(const float* __restrict__ x, _Float16* __restrict__ h,
                             float* __restrict__ x0, int n) {
  int idx = blockIdx.x * blockDim.x + threadIdx.x;
  if (idx < n * 128) {
    int node = idx >> 7;
    int k = idx & 127;
    h[idx] = (_Float16)x[(size_t)node * 129 + 1 + k];
  }
  if (idx < n) x0[idx] = x[(size_t)idx * 129];
}

// ---- MFMA head: out = sigmoid( relu(h@W1[hrow0:+128] + extra*W1[xrow] + b1)
//      @ w2 + b2 ) -----------------------------------------------------------
__global__ __launch_bounds__(256) void head_mfma_kernel(const _Float16* __restrict__ h,
    const float* __restrict__ extra, const float* __restrict__ W1,
    const float* __restrict__ b1, const float* __restrict__ w2,
    const float* __restrict__ b2, float* __restrict__ out, int n,
    int hrow0, int xrow) {
  __shared__ __align__(16) _Float16 sB[4 * 4 * 64 * 8];  // 16 KB, B-frag order
  __shared__ float sWx[64], sB1[64], sW2[64];
  for (int idx = threadIdx.x; idx < 8192; idx += 256) {
    int k = idx >> 6, col = idx & 63;
    float w = W1[(size_t)(hrow0 + k) * 64 + col];
    int ks = k >> 5, quad = (k >> 3) & 3, j = k & 7;
    int nt = col >> 4, cl = col & 15;
    sB[(((ks * 4 + nt) * 64) + quad * 16 + cl) * 8 + j] = (_Float16)w;
  }
  if (threadIdx.x < 64) {
    sWx[threadIdx.x] = W1[(size_t)xrow * 64 + threadIdx.x];
    sB1[threadIdx.x] = b1[threadIdx.x];
    sW2[threadIdx.x] = w2[threadIdx.x];
  }
  __syncthreads();
  int wv = threadIdx.x >> 6, lane = threadIdx.x & 63;
  int quad = lane >> 4, l15 = lane & 15;
  int n0 = (blockIdx.x * 4 + wv) * 16;
  if (n0 >= n) return;
  int node_a = min(n0 + l15, n - 1);
  const _Float16* hrow = h + (size_t)node_a * 128 + quad * 8;

  f32x4 acc[4];
#pragma unroll
  for (int t = 0; t < 4; t++) acc[t] = (f32x4){0.f, 0.f, 0.f, 0.f};
  for (int ks = 0; ks < 4; ks++) {
    f16x8 afrag = *(const f16x8*)(hrow + ks * 32);
    const f16x8* bp = (const f16x8*)sB;
#pragma unroll
    for (int t = 0; t < 4; t++) {
      f16x8 bfrag = bp[(ks * 4 + t) * 64 + lane];
      acc[t] = __builtin_amdgcn_mfma_f32_16x16x32_f16(afrag, bfrag, acc[t], 0, 0, 0);
    }
  }
  float b2v = b2[0];
  float xv[4], part[4] = {0.f, 0.f, 0.f, 0.f};
#pragma unroll
  for (int r = 0; r < 4; r++) xv[r] = extra[min(n0 + quad * 4 + r, n - 1)];
#pragma unroll
  for (int t = 0; t < 4; t++) {
    int col = t * 16 + l15;
    float wx = sWx[col], bb = sB1[col], w2v = sW2[col];
#pragma unroll
    for (int r = 0; r < 4; r++) {
      float u = fmaxf(acc[t][r] + xv[r] * wx + bb, 0.f);
      part[r] += u * w2v;
    }
  }
#pragma unroll
  for (int r = 0; r < 4; r++) {
    float p = part[r];
    p += __shfl_xor(p, 1); p += __shfl_xor(p, 2);
    p += __shfl_xor(p, 4); p += __shfl_xor(p, 8);
    int node = n0 + quad * 4 + r;
    if (l15 == 0 && node < n) out[node] = sigmoidf_(p + b2v);
  }
}

// ---- MFMA GEMM: ht8/scales = rowquant(h16 @ W + b) -------------------------
__global__ __launch_bounds__(256) void gemm_mfma_kernel(const _Float16* __restrict__ h,
    const float* __restrict__ Wg, const float* __restrict__ b,
    unsigned char* __restrict__ out8, float* __restrict__ scales, int n) {
  __shared__ __align__(16) _Float16 sB[4 * 8 * 64 * 8];  // 32 KB
  for (int i = threadIdx.x; i < 4096; i += 256) {  // i = float4 index over W
    int k = i >> 5;
    int n4 = (i & 31) * 4;
    float4 w4 = ((const float4*)Wg)[i];
    int ks = k >> 5, quad = (k >> 3) & 3, j = k & 7;
#pragma unroll
    for (int c = 0; c < 4; c++) {
      int col = n4 + c;
      int nt = col >> 4, cl = col & 15;
      sB[(((ks * 8 + nt) * 64) + quad * 16 + cl) * 8 + j] =
          (_Float16)((const float*)&w4)[c];
    }
  }
  __syncthreads();
  int wv = threadIdx.x >> 6, lane = threadIdx.x & 63;
  int quad = lane >> 4, l15 = lane & 15;
  int tiles = (n + 63) >> 6;
  for (int tile = blockIdx.x; tile < tiles; tile += gridDim.x) {
    int n0 = (tile * 4 + wv) * 16;
    if (n0 >= n) continue;
    int node_a = min(n0 + l15, n - 1);
    const _Float16* hrow = h + (size_t)node_a * 128 + quad * 8;

    f32x4 acc[8];
#pragma unroll
    for (int t = 0; t < 8; t++) acc[t] = (f32x4){0.f, 0.f, 0.f, 0.f};

    for (int ks = 0; ks < 4; ks++) {
      f16x8 afrag = *(const f16x8*)(hrow + ks * 32);
      const f16x8* bp = (const f16x8*)(sB + ks * 8 * 64 * 8);
#pragma unroll
      for (int t = 0; t < 8; t++) {
        f16x8 bfrag = bp[t * 64 + lane];
        acc[t] = __builtin_amdgcn_mfma_f32_16x16x32_f16(afrag, bfrag, acc[t], 0, 0, 0);
      }
    }
#pragma unroll
    for (int t = 0; t < 8; t++) {
      float bias = b[t * 16 + l15];
#pragma unroll
      for (int r = 0; r < 4; r++) acc[t][r] += bias;
    }
    float mx[4] = {0.f, 0.f, 0.f, 0.f};
#pragma unroll
    for (int t = 0; t < 8; t++)
#pragma unroll
      for (int r = 0; r < 4; r++) mx[r] = fmaxf(mx[r], fabsf(acc[t][r]));
#pragma unroll
    for (int m = 1; m <= 8; m <<= 1) {
#pragma unroll
      for (int r = 0; r < 4; r++) mx[r] = fmaxf(mx[r], __shfl_xor(mx[r], m));
    }
#pragma unroll
    for (int r = 0; r < 4; r++) {
      int node = n0 + quad * 4 + r;
      if (node >= n) continue;
      float inv = (mx[r] > 0.f) ? 127.f / mx[r] : 0.f;
      if (l15 == 0) scales[node] = mx[r] * (1.f / 127.f);
#pragma unroll
      for (int t = 0; t < 8; t++) {
        int u = (int)rintf(acc[t][r] * inv) + 128;
        u = min(max(u, 0), 255);
        out8[(size_t)node * 128 + t * 16 + l15] = (unsigned char)u;
      }
    }
  }
}

// ---- aggregation: int8 rows, edge-pair halves, absolute starts -------------
template <int LAYER>
__device__ __forceinline__ float gate_(uint2 r) {
  const float inv = 1.f / 32767.f;
  if (LAYER == 0) return (float)(r.x >> 17) * inv;
  if (LAYER == 1) return (float)(r.y & 0x7fffu) * inv;
  return (float)(r.y >> 15) * inv;
}

#define ACC4(u, g)                                   \
  a0 += (float)((u) & 0xffu) * (g);                  \
  a1 += (float)(((u) >> 8) & 0xffu) * (g);           \
  a2 += (float)(((u) >> 16) & 0xffu) * (g);          \
  a3 += (float)((u) >> 24) * (g);

template <int LAYER>
__global__ __launch_bounds__(256) void agg_kernel(const unsigned char* __restrict__ ht8,
    const float* __restrict__ scales, const uint2* __restrict__ csr,
    const int* __restrict__ starts, const float* __restrict__ wp,
    __half2* __restrict__ hout, int n) {
  int wv = threadIdx.x >> 6, lane = threadIdx.x & 63;
  int node = blockIdx.x * 4 + wv;
  if (node >= n) return;
  int s = starts[node];
  int c = starts[node + 1] - s;
  float gs = sigmoidf_(wp[0]);
  int sub = lane & 31, p = lane >> 5;
  unsigned sub4 = (unsigned)sub * 4u;

  unsigned su = *(const unsigned*)(ht8 + (unsigned)node * 128u + sub4);
  float gsc = (p == 0) ? gs * scales[node] : 0.f;
  float sgs = gsc;
  float a0 = 0.f, a1 = 0.f, a2 = 0.f, a3 = 0.f;
  ACC4(su, gsc)

  int j = 0;
  for (; j + 16 <= c; j += 16) {
    uint2 r0 = csr[s + j + 0 + p],  r1 = csr[s + j + 2 + p];
    uint2 r2 = csr[s + j + 4 + p],  r3 = csr[s + j + 6 + p];
    uint2 r4 = csr[s + j + 8 + p],  r5 = csr[s + j + 10 + p];
    uint2 r6 = csr[s + j + 12 + p], r7 = csr[s + j + 14 + p];
    unsigned i0 = r0.x & 0x1ffffu, i1 = r1.x & 0x1ffffu;
    unsigned i2 = r2.x & 0x1ffffu, i3 = r3.x & 0x1ffffu;
    unsigned i4 = r4.x & 0x1ffffu, i5 = r5.x & 0x1ffffu;
    unsigned i6 = r6.x & 0x1ffffu, i7 = r7.x & 0x1ffffu;
    unsigned u0 = *(const unsigned*)(ht8 + i0 * 128u + sub4);
    unsigned u1 = *(const unsigned*)(ht8 + i1 * 128u + sub4);
    unsigned u2 = *(const unsigned*)(ht8 + i2 * 128u + sub4);
    unsigned u3 = *(const unsigned*)(ht8 + i3 * 128u + sub4);
    unsigned u4 = *(const unsigned*)(ht8 + i4 * 128u + sub4);
    unsigned u5 = *(const unsigned*)(ht8 + i5 * 128u + sub4);
    unsigned u6 = *(const unsigned*)(ht8 + i6 * 128u + sub4);
    unsigned u7 = *(const unsigned*)(ht8 + i7 * 128u + sub4);
    float g0 = gate_<LAYER>(r0) * scales[i0];
    float g1 = gate_<LAYER>(r1) * scales[i1];
    float g2 = gate_<LAYER>(r2) * scales[i2];
    float g3 = gate_<LAYER>(r3) * scales[i3];
    float g4 = gate_<LAYER>(r4) * scales[i4];
    float g5 = gate_<LAYER>(r5) * scales[i5];
    float g6 = gate_<LAYER>(r6) * scales[i6];
    float g7 = gate_<LAYER>(r7) * scales[i7];
    sgs += g0 + g1 + g2 + g3 + g4 + g5 + g6 + g7;
    ACC4(u0, g0) ACC4(u1, g1) ACC4(u2, g2) ACC4(u3, g3)
    ACC4(u4, g4) ACC4(u5, g5) ACC4(u6, g6) ACC4(u7, g7)
  }
  for (; j + 8 <= c; j += 8) {
    uint2 r0 = csr[s + j + 0 + p], r1 = csr[s + j + 2 + p];
    uint2 r2 = csr[s + j + 4 + p], r3 = csr[s + j + 6 + p];
    unsigned i0 = r0.x & 0x1ffffu, i1 = r1.x & 0x1ffffu;
    unsigned i2 = r2.x & 0x1ffffu, i3 = r3.x & 0x1ffffu;
    unsigned u0 = *(const unsigned*)(ht8 + i0 * 128u + sub4);
    unsigned u1 = *(const unsigned*)(ht8 + i1 * 128u + sub4);
    unsigned u2 = *(const unsigned*)(ht8 + i2 * 128u + sub4);
    unsigned u3 = *(const unsigned*)(ht8 + i3 * 128u + sub4);
    float g0 = gate_<LAYER>(r0) * scales[i0];
    float g1 = gate_<LAYER>(r1) * scales[i1];
    float g2 = gate_<LAYER>(r2) * scales[i2];
    float g3 = gate_<LAYER>(r3) * scales[i3];
    sgs += g0 + g1 + g2 + g3;
    ACC4(u0, g0) ACC4(u1, g1) ACC4(u2, g2) ACC4(u3, g3)
  }
  for (; j + 2 <= c; j += 2) {
    uint2 r = csr[s + j + p];
    unsigned i0 = r.x & 0x1ffffu;
    unsigned u = *(const unsigned*)(ht8 + i0 * 128u + sub4);
    float g = gate_<LAYER>(r) * scales[i0];
    sgs += g;
    ACC4(u, g)
  }
  if (j < c) {
    uint2 r = csr[s + j];
    unsigned i0 = r.x & 0x1ffffu;
    unsigned u = *(const unsigned*)(ht8 + i0 * 128u + sub4);
    float g = (p == 0) ? gate_<LAYER>(r) * scales[i0] : 0.f;
    sgs += g;
    ACC4(u, g)
  }
  a0 += __shfl_xor(a0, 32); a1 += __shfl_xor(a1, 32);
  a2 += __shfl_xor(a2, 32); a3 += __shfl_xor(a3, 32);
  sgs += __shfl_xor(sgs, 32);
  float corr = 128.f * sgs;
  float inv = 1.f / (float)(c + 1);
  a0 = fmaxf((a0 - corr) * inv, 0.f);
  a1 = fmaxf((a1 - corr) * inv, 0.f);
  a2 = fmaxf((a2 - corr) * inv, 0.f);
  a3 = fmaxf((a3 - corr) * inv, 0.f);
  if (p == 0) {
    __half2 h01 = __floats2half2_rn(a0, a1);
    __half2 h23 = __floats2half2_rn(a2, a3);
    uint2 outw;
    outw.x = *(unsigned*)&h01;
    outw.y = *(unsigned*)&h23;
    *(uint2*)((char*)hout + (size_t)node * 256 + (size_t)sub * 8) = outw;
  }
}

// ---------------------------------------------------------------------------
extern "C" void kernel_launch(void* const* d_in, const int* in_sizes, int n_in,
                              void* d_out, int out_size, void* d_ws, size_t ws_size,
                              hipStream_t stream) {
  int ob = (out_size + 255) / 256;

  const float *x, *ea, *l1W, *l1b, *l2W, *l2b, *t1W, *t1b, *t2W, *t2b;
  const float *convW[3], *convb[3], *edgew[3];
  const int* ei;

  if (n_in == 20) {          // tuples flattened to separate entries
    x = (const float*)d_in[0]; ei = (const int*)d_in[1]; ea = (const float*)d_in[2];
    for (int l = 0; l < 3; l++) {
      convW[l] = (const float*)d_in[3 + l];
      convb[l] = (const float*)d_in[6 + l];
      edgew[l] = (const float*)d_in[9 + l];
    }
    l1W = (const float*)d_in[12]; l1b = (const float*)d_in[13];
    l2W = (const float*)d_in[14]; l2b = (const float*)d_in[15];
    t1W = (const float*)d_in[16]; t1b = (const float*)d_in[17];
    t2W = (const float*)d_in[18]; t2b = (const float*)d_in[19];
  } else if (n_in == 14) {   // each tuple is ONE concatenated buffer
    x = (const float*)d_in[0]; ei = (const int*)d_in[1]; ea = (const float*)d_in[2];
    const float* cw = (const float*)d_in[3];
    const float* cb = (const float*)d_in[4];
    const float* ew = (const float*)d_in[5];
    for (int l = 0; l < 3; l++) {
      convW[l] = cw + (size_t)l * 128 * 128;
      convb[l] = cb + (size_t)l * 128;
      edgew[l] = ew + l;
    }
    l1W = (const float*)d_in[6];  l1b = (const float*)d_in[7];
    l2W = (const float*)d_in[8];  l2b = (const float*)d_in[9];
    t1W = (const float*)d_in[10]; t1b = (const float*)d_in[11];
    t2W = (const float*)d_in[12]; t2b = (const float*)d_in[13];
  } else {
    sentinel_kernel<<<ob, 256, 0, stream>>>((float*)d_out, out_size,
                                            900.0f + (float)n_in);
    return;
  }

  int n = in_sizes[0] / 129;   // 100000
  int E = in_sizes[2];         // 1600000

  int nblocksA = (E + EPB - 1) / EPB;  // 1563 (must be <= 4096)
  int NB = (n + 255) >> 8;             // 391 coarse bins (must be <= 512)

  char* ws = (char*)d_ws;
  size_t off = 0;
  auto take = [&](size_t bytes) -> void* {
    void* p = ws + off;
    off = (off + bytes + 255) & ~(size_t)255;
    return p;
  };
  int*      flag    = (int*)take(256);
  int*      histA   = (int*)take((size_t)NB * nblocksA * 4);  // ~2.4 MB
  int*      binTot  = (int*)take((size_t)NB * 4);
  int*      binBase = (int*)take(((size_t)NB + 1) * 4);
  int*      starts  = (int*)take(((size_t)n + 1) * 4);
  uint2*    brec    = (uint2*)take((size_t)E * 8);            // 12.8 MB
  unsigned char* bkey = (unsigned char*)take((size_t)E);      // 1.6 MB
  uint2*    csr     = (uint2*)take((size_t)E * 8);            // 12.8 MB
  float*    tbuf    = (float*)take((size_t)n * 4);
  float*    x0buf   = (float*)take((size_t)n * 4);
  _Float16* h16     = (_Float16*)take((size_t)n * 128 * 2);   // 25.6 MB
  unsigned char* ht8 = (unsigned char*)take((size_t)n * 128); // 12.8 MB
  float*    scales  = (float*)take((size_t)n * 4);            // 400 KB

  if (off > ws_size || nblocksA > 4096 || NB > 512) {
    sentinel_kernel<<<ob, 256, 0, stream>>>((float*)d_out, out_size,
                                            1000.0f + (float)(ws_size >> 20));
    return;
  }

  int sb = (int)(((size_t)n * 128 + 255) / 256);  // slice blocks
  int hgrid = (n + 63) / 64;                      // head blocks

  flag_kernel<<<1, 64, 0, stream>>>(ei, flag);
  hist_kernel<<<nblocksA, 256, 0, stream>>>(ei, E, n, flag, histA, nblocksA, NB);
  scanrow_kernel<<<NB, 256, 0, stream>>>(histA, nblocksA, binTot);
  binbase_kernel<<<1, 512, 0, stream>>>(binTot, NB, binBase, starts, n);
  reorder_kernel<<<nblocksA, 256, 0, stream>>>(ei, ea, E, n, flag, histA, nblocksA,
                                               binBase, edgew[0], edgew[1], edgew[2],
                                               brec, bkey, NB);
  fine_kernel<<<NB, 256, 0, stream>>>(brec, bkey, binBase, n, csr, starts);

  slice_kernel<<<sb, 256, 0, stream>>>(x, h16, x0buf, n);
  // tnet: W1=t1W (129x64), h-rows 1..128, extra=x0 via row 0
  head_mfma_kernel<<<hgrid, 256, 0, stream>>>(h16, x0buf, t1W, t1b, t2W, t2b,
                                              tbuf, n, 1, 0);

  int gemm_grid = min((n + 63) / 64, 1024);
  gemm_mfma_kernel<<<gemm_grid, 256, 0, stream>>>(h16, convW[0], convb[0], ht8, scales, n);
  agg_kernel<0><<<(n + 3) / 4, 256, 0, stream>>>(ht8, scales, csr, starts,
                                                 edgew[0], (__half2*)h16, n);
  gemm_mfma_kernel<<<gemm_grid, 256, 0, stream>>>(h16, convW[1], convb[1], ht8, scales, n);
  agg_kernel<1><<<(n + 3) / 4, 256, 0, stream>>>(ht8, scales, csr, starts,
                                                 edgew[1], (__half2*)h16, n);
  gemm_mfma_kernel<<<gemm_grid, 256, 0, stream>>>(h16, convW[2], convb[2], ht8, scales, n);
  agg_kernel<2><<<(n + 3) / 4, 256, 0, stream>>>(ht8, scales, csr, starts,
                                                 edgew[2], (__half2*)h16, n);

  // mlp: W1=l1W (129x64), h-rows 0..127, extra=t via row 128
  head_mfma_kernel<<<hgrid, 256, 0, stream>>>(h16, tbuf, l1W, l1b, l2W, l2b,
                                              (float*)d_out, n, 0, 128);
}